// Round 1
// baseline (6348.025 us; speedup 1.0000x reference)
//
#include <hip/hip_runtime.h>
#include <math.h>

#define BATCH 4
#define NP    2048
#define NP1   2049
#define KNNK  20
#define DEMB  512
#define NH    4
#define DHD   128

// ---------------------------------------------------------------- kNN top-20
__global__ void knn_kernel(const float* __restrict__ x, int* __restrict__ idx_out) {
  int b = blockIdx.x / NP, n = blockIdx.x % NP, t = threadIdx.x;
  __shared__ float xs0[NP], xs1[NP], xs2[NP];
  __shared__ float nd[NP];
  __shared__ float rv[256];
  __shared__ int   ri[256];
  const float* xb = x + (size_t)b * 3 * NP;
  for (int m = t; m < NP; m += 256) {
    xs0[m] = xb[m]; xs1[m] = xb[NP + m]; xs2[m] = xb[2 * NP + m];
  }
  __syncthreads();
  float c0 = xs0[n], c1 = xs1[n], c2 = xs2[n];
  float xxn = c0 * c0 + c1 * c1 + c2 * c2;
  for (int m = t; m < NP; m += 256) {
    float a0 = xs0[m], a1 = xs1[m], a2 = xs2[m];
    float inner = c0 * a0 + c1 * a1 + c2 * a2;
    float xxm = a0 * a0 + a1 * a1 + a2 * a2;
    nd[m] = 2.f * inner - xxn - xxm;
  }
  __syncthreads();
  int* orow = idx_out + ((size_t)b * NP + n) * KNNK;
  for (int it = 0; it < KNNK; ++it) {
    float bv = -INFINITY; int bi = -1;
    for (int m = t; m < NP; m += 256) {
      float v = nd[m];
      if (v > bv || (v == bv && m < bi)) { bv = v; bi = m; }
    }
    rv[t] = bv; ri[t] = bi;
    __syncthreads();
    for (int s = 128; s > 0; s >>= 1) {
      if (t < s) {
        float ov = rv[t + s]; int oi = ri[t + s];
        if (ov > rv[t] || (ov == rv[t] && oi < ri[t])) { rv[t] = ov; ri[t] = oi; }
      }
      __syncthreads();
    }
    if (t == 0) { orow[it] = ri[0]; nd[ri[0]] = -INFINITY; }
    __syncthreads();
  }
}

// ---------------------------------------------------------------- fused GAC (one block per point)
__global__ void gac_kernel(const float* __restrict__ x, const int* __restrict__ idx,
                           const float* __restrict__ w1, const float* __restrict__ s1, const float* __restrict__ b1,
                           const float* __restrict__ w2, const float* __restrict__ s2, const float* __restrict__ b2,
                           const float* __restrict__ wo, const float* __restrict__ so, const float* __restrict__ bo,
                           float* __restrict__ dout) {
  int b = blockIdx.x / NP, n = blockIdx.x % NP, t = threadIdx.x;
  __shared__ float g[6][KNNK];
  __shared__ float h1[64][KNNK + 1];
  __shared__ float h2[128][KNNK + 1];
  __shared__ float xc[192];
  __shared__ float w1s[64 * 6];
  __shared__ float w2s[128 * 64];
  for (int i = t; i < 64 * 6; i += 256)  w1s[i] = w1[i];
  for (int i = t; i < 128 * 64; i += 256) w2s[i] = w2[i];
  const float* xb = x + (size_t)b * 3 * NP;
  if (t < KNNK) {
    int j = idx[((size_t)b * NP + n) * KNNK + t];
    float c0 = xb[n], c1 = xb[NP + n], c2 = xb[2 * NP + n];
    float f0 = xb[j], f1 = xb[NP + j], f2 = xb[2 * NP + j];
    g[0][t] = f0 - c0; g[1][t] = f1 - c1; g[2][t] = f2 - c2;
    g[3][t] = c0; g[4][t] = c1; g[5][t] = c2;
  }
  __syncthreads();
  for (int item = t; item < 64 * KNNK; item += 256) {
    int o = item / KNNK, k = item % KNNK;
    float y = 0.f;
#pragma unroll
    for (int c = 0; c < 6; ++c) y += w1s[o * 6 + c] * g[c][k];
    y = y * s1[o] + b1[o];
    h1[o][k] = fmaxf(y, 0.f);
  }
  __syncthreads();
  if (t < 64) {
    float mx = -INFINITY;
    for (int k = 0; k < KNNK; ++k) mx = fmaxf(mx, h1[t][k]);
    float se = 0.f, sh = 0.f;
    for (int k = 0; k < KNNK; ++k) { float e = expf(h1[t][k] - mx); se += e; sh += h1[t][k] * e; }
    xc[t] = sh / se;
  }
  __syncthreads();
  for (int item = t; item < 128 * KNNK; item += 256) {
    int o = item / KNNK, k = item % KNNK;
    float y = 0.f;
    for (int c = 0; c < 64; ++c) y += w2s[o * 64 + c] * h1[c][k];
    y = y * s2[o] + b2[o];
    h2[o][k] = fmaxf(y, 0.f);
  }
  __syncthreads();
  if (t < 128) {
    float mx = -INFINITY;
    for (int k = 0; k < KNNK; ++k) mx = fmaxf(mx, h2[t][k]);
    float se = 0.f, sh = 0.f;
    for (int k = 0; k < KNNK; ++k) { float e = expf(h2[t][k] - mx); se += e; sh += h2[t][k] * e; }
    xc[64 + t] = sh / se;
  }
  __syncthreads();
  for (int o = t; o < DEMB; o += 256) {
    float y = 0.f;
    for (int c = 0; c < 192; ++c) y += wo[o * 192 + c] * xc[c];
    y = y * so[o] + bo[o];
    dout[((size_t)b * DEMB + o) * NP + n] = fmaxf(y, 0.f);
  }
}

// ---------------------------------------------------------------- GEMM: Y = W(512xC) @ X(B,C,N) + bias
// HEADS=1: write (B,H,N,DH) layout (c -> h=c&3, dh=c>>2); HEADS=0: (B,512,N)
template <int HEADS>
__global__ void gemm_bias_kernel(const float* __restrict__ W, const float* __restrict__ bias,
                                 const float* __restrict__ X, float* __restrict__ Y, int C) {
  int n0 = blockIdx.x * 64, o0 = blockIdx.y * 64, b = blockIdx.z;
  int t = threadIdx.x, tx = t & 15, ty = t >> 4;
  __shared__ float Ws[16][65];
  __shared__ float Xs[16][65];
  float acc[4][4] = {};
  const float* Xb = X + (size_t)b * C * NP;
  for (int k0 = 0; k0 < C; k0 += 16) {
#pragma unroll
    for (int u = 0; u < 4; ++u) {
      int li = t + 256 * u;
      int i = li >> 4, j = li & 15;
      Ws[j][i] = W[(size_t)(o0 + i) * C + k0 + j];
      int i2 = li & 63, j2 = li >> 6;
      Xs[j2][i2] = Xb[(size_t)(k0 + j2) * NP + n0 + i2];
    }
    __syncthreads();
#pragma unroll
    for (int k = 0; k < 16; ++k) {
      float a[4], bb[4];
#pragma unroll
      for (int ii = 0; ii < 4; ++ii) a[ii] = Ws[k][ty + 16 * ii];
#pragma unroll
      for (int jj = 0; jj < 4; ++jj) bb[jj] = Xs[k][tx + 16 * jj];
#pragma unroll
      for (int ii = 0; ii < 4; ++ii)
#pragma unroll
        for (int jj = 0; jj < 4; ++jj) acc[ii][jj] += a[ii] * bb[jj];
    }
    __syncthreads();
  }
#pragma unroll
  for (int ii = 0; ii < 4; ++ii) {
    int o = o0 + ty + 16 * ii;
    float bv = bias[o];
#pragma unroll
    for (int jj = 0; jj < 4; ++jj) {
      int n = n0 + tx + 16 * jj;
      float v = acc[ii][jj] + bv;
      if (HEADS) {
        int h = o & 3, dh = o >> 2;
        Y[(((size_t)b * NH + h) * NP + n) * DHD + dh] = v;
      } else {
        Y[((size_t)b * DEMB + o) * NP + n] = v;
      }
    }
  }
}

// ---------------------------------------------------------------- MLP: Y = D + W(512x1024) @ [Xa;Xb]
__global__ void gemm_mlp_kernel(const float* __restrict__ W, const float* __restrict__ Xa,
                                const float* __restrict__ Xb, const float* __restrict__ D,
                                float* __restrict__ Y) {
  int n0 = blockIdx.x * 64, o0 = blockIdx.y * 64, b = blockIdx.z;
  int t = threadIdx.x, tx = t & 15, ty = t >> 4;
  __shared__ float Ws[16][65];
  __shared__ float Xs[16][65];
  float acc[4][4] = {};
  const float* Xab = Xa + (size_t)b * DEMB * NP;
  const float* Xbb = Xb + (size_t)b * DEMB * NP;
  for (int k0 = 0; k0 < 1024; k0 += 16) {
    const float* src = (k0 < 512) ? (Xab + (size_t)k0 * NP) : (Xbb + (size_t)(k0 - 512) * NP);
#pragma unroll
    for (int u = 0; u < 4; ++u) {
      int li = t + 256 * u;
      int i = li >> 4, j = li & 15;
      Ws[j][i] = W[(size_t)(o0 + i) * 1024 + k0 + j];
      int i2 = li & 63, j2 = li >> 6;
      Xs[j2][i2] = src[(size_t)j2 * NP + n0 + i2];
    }
    __syncthreads();
#pragma unroll
    for (int k = 0; k < 16; ++k) {
      float a[4], bb[4];
#pragma unroll
      for (int ii = 0; ii < 4; ++ii) a[ii] = Ws[k][ty + 16 * ii];
#pragma unroll
      for (int jj = 0; jj < 4; ++jj) bb[jj] = Xs[k][tx + 16 * jj];
#pragma unroll
      for (int ii = 0; ii < 4; ++ii)
#pragma unroll
        for (int jj = 0; jj < 4; ++jj) acc[ii][jj] += a[ii] * bb[jj];
    }
    __syncthreads();
  }
#pragma unroll
  for (int ii = 0; ii < 4; ++ii) {
    int o = o0 + ty + 16 * ii;
#pragma unroll
    for (int jj = 0; jj < 4; ++jj) {
      int n = n0 + tx + 16 * jj;
      size_t oi = ((size_t)b * DEMB + o) * NP + n;
      Y[oi] = acc[ii][jj] + D[oi];
    }
  }
}

// ---------------------------------------------------------------- flash attention (Q,K,V in (B,H,N,DH))
__global__ void attn_kernel(const float* __restrict__ Q, const float* __restrict__ Kx,
                            const float* __restrict__ Vx, float* __restrict__ att) {
  int blk = blockIdx.x;
  int qt = blk % (NP / 32), bh = blk / (NP / 32);
  int t = threadIdx.x;
  int q = t >> 3, mg = t & 7;
  __shared__ float Qs[32][129];
  __shared__ float Ks[32][129];
  __shared__ float Vs[32][129];
  __shared__ float Ps[32][33];
  const float* Qb = Q + ((size_t)bh * NP + qt * 32) * DHD;
  const float* Kb = Kx + (size_t)bh * NP * DHD;
  const float* Vb = Vx + (size_t)bh * NP * DHD;
  for (int li = t; li < 32 * DHD; li += 256) Qs[li >> 7][li & 127] = Qb[li];
  float acc[16] = {};
  float mrun = -INFINITY, lrun = 0.f;
  const float scale = 0.08838834764831845f; // 1/sqrt(128)
  for (int m0 = 0; m0 < NP; m0 += 32) {
    __syncthreads();
    for (int li = t; li < 32 * DHD; li += 256) {
      Ks[li >> 7][li & 127] = Kb[(size_t)m0 * DHD + li];
      Vs[li >> 7][li & 127] = Vb[(size_t)m0 * DHD + li];
    }
    __syncthreads();
    float sv[4] = {0.f, 0.f, 0.f, 0.f};
    for (int d = 0; d < DHD; ++d) {
      float qd = Qs[q][d];
#pragma unroll
      for (int mi = 0; mi < 4; ++mi) sv[mi] += qd * Ks[mg * 4 + mi][d];
    }
    float tmax = -INFINITY;
#pragma unroll
    for (int mi = 0; mi < 4; ++mi) { sv[mi] *= scale; tmax = fmaxf(tmax, sv[mi]); }
    for (int s = 1; s < 8; s <<= 1) tmax = fmaxf(tmax, __shfl_xor(tmax, s));
    float mnew = fmaxf(mrun, tmax);
    float factor = expf(mrun - mnew);
    float psum = 0.f;
#pragma unroll
    for (int mi = 0; mi < 4; ++mi) { float p = expf(sv[mi] - mnew); Ps[q][mg * 4 + mi] = p; psum += p; }
    for (int s = 1; s < 8; s <<= 1) psum += __shfl_xor(psum, s);
    lrun = lrun * factor + psum;
    mrun = mnew;
#pragma unroll
    for (int dd = 0; dd < 16; ++dd) acc[dd] *= factor;
    __syncthreads();
    for (int m = 0; m < 32; ++m) {
      float p = Ps[q][m];
#pragma unroll
      for (int dd = 0; dd < 16; ++dd) acc[dd] += p * Vs[m][mg + 8 * dd];
    }
  }
  float linv = 1.f / lrun;
  int b = bh / NH, h = bh % NH;
  int n = qt * 32 + q;
#pragma unroll
  for (int dd = 0; dd < 16; ++dd) {
    int dh = mg + 8 * dd;
    att[((size_t)b * DEMB + (dh * NH + h)) * NP + n] = acc[dd] * linv;
  }
}

// ---------------------------------------------------------------- dists -> padded sinkhorn buffer
__global__ void dists_kernel(const float* __restrict__ A, const float* __restrict__ Bm,
                             float* __restrict__ S) {
  int m0 = blockIdx.x * 64, n0 = blockIdx.y * 64, b = blockIdx.z;
  int t = threadIdx.x, tx = t & 15, ty = t >> 4;
  __shared__ float As[16][65];
  __shared__ float Bs[16][65];
  float acc[4][4] = {};
  const float* Ab = A + (size_t)b * DEMB * NP;
  const float* Bb = Bm + (size_t)b * DEMB * NP;
  for (int k0 = 0; k0 < DEMB; k0 += 16) {
#pragma unroll
    for (int u = 0; u < 4; ++u) {
      int li = t + 256 * u;
      int i2 = li & 63, j2 = li >> 6;
      As[j2][i2] = Ab[(size_t)(k0 + j2) * NP + n0 + i2];
      Bs[j2][i2] = Bb[(size_t)(k0 + j2) * NP + m0 + i2];
    }
    __syncthreads();
#pragma unroll
    for (int k = 0; k < 16; ++k) {
      float a[4], bb[4];
#pragma unroll
      for (int ii = 0; ii < 4; ++ii) a[ii] = As[k][ty + 16 * ii];
#pragma unroll
      for (int jj = 0; jj < 4; ++jj) bb[jj] = Bs[k][tx + 16 * jj];
#pragma unroll
      for (int ii = 0; ii < 4; ++ii)
#pragma unroll
        for (int jj = 0; jj < 4; ++jj) acc[ii][jj] += a[ii] * bb[jj];
    }
    __syncthreads();
  }
  const float scale = 0.04419417382415922f; // 1/sqrt(512)
#pragma unroll
  for (int ii = 0; ii < 4; ++ii) {
    int n = n0 + ty + 16 * ii;
#pragma unroll
    for (int jj = 0; jj < 4; ++jj) {
      int m = m0 + tx + 16 * jj;
      S[(size_t)b * NP1 * NP1 + (size_t)n * NP1 + m] = acc[ii][jj] * scale;
    }
  }
}

__global__ void sink_pad_kernel(float* __restrict__ S) {
  int i = blockIdx.x * 256 + threadIdx.x;
  if (i >= BATCH * NP1) return;
  int b = i / NP1, r = i % NP1;
  S[((size_t)b * NP1 + r) * NP1 + NP] = 0.f;
  S[((size_t)b * NP1 + NP) * NP1 + r] = 0.f;
}

// rows 0..2047: subtract logsumexp over 2049 columns
__global__ void sink_row_kernel(float* __restrict__ S) {
  int b = blockIdx.x / NP, r = blockIdx.x % NP, t = threadIdx.x;
  float* row = S + ((size_t)b * NP1 + r) * NP1;
  __shared__ float rm[256], rs[256];
  float m = -INFINITY, s = 0.f;
  for (int c = t; c < NP1; c += 256) {
    float x = row[c];
    float nm = fmaxf(m, x);
    s = s * expf(m - nm) + expf(x - nm);
    m = nm;
  }
  rm[t] = m; rs[t] = s;
  __syncthreads();
  for (int st = 128; st > 0; st >>= 1) {
    if (t < st) {
      float m2 = rm[t + st], s2 = rs[t + st];
      float M = fmaxf(rm[t], m2);
      rs[t] = rs[t] * expf(rm[t] - M) + s2 * expf(m2 - M);
      rm[t] = M;
    }
    __syncthreads();
  }
  float lse = rm[0] + logf(rs[0]);
  for (int c = t; c < NP1; c += 256) row[c] -= lse;
}

// col pass 1: partial (max,sum) per (col, row-chunk)
__global__ void sink_col1_kernel(const float* __restrict__ S, float* __restrict__ colM,
                                 float* __restrict__ colS) {
  int ctile = blockIdx.x, part = blockIdx.y, b = blockIdx.z;
  int t = threadIdx.x, ry = t >> 6, cx = t & 63;
  int c = ctile * 64 + cx;
  int r0 = part * 256, r1 = (part == 7) ? NP1 : (r0 + 256);
  const float* Sb = S + (size_t)b * NP1 * NP1;
  float m = -INFINITY, s = 0.f;
  for (int r = r0 + ry; r < r1; r += 4) {
    float x = Sb[(size_t)r * NP1 + c];
    float nm = fmaxf(m, x);
    s = s * expf(m - nm) + expf(x - nm);
    m = nm;
  }
  __shared__ float pm[4][64], ps[4][64];
  pm[ry][cx] = m; ps[ry][cx] = s;
  __syncthreads();
  if (ry == 0) {
    for (int k = 1; k < 4; ++k) {
      float m2 = pm[k][cx], s2 = ps[k][cx];
      float M = fmaxf(m, m2);
      s = s * expf(m - M) + s2 * expf(m2 - M);
      m = M;
    }
    size_t o = ((size_t)b * NP + c) * 8 + part;
    colM[o] = m; colS[o] = s;
  }
}

__global__ void sink_col2_kernel(const float* __restrict__ colM, const float* __restrict__ colS,
                                 float* __restrict__ colL) {
  int i = blockIdx.x * 256 + threadIdx.x;
  if (i >= BATCH * NP) return;
  float m = -INFINITY, s = 0.f;
  for (int p = 0; p < 8; ++p) {
    float m2 = colM[(size_t)i * 8 + p], s2 = colS[(size_t)i * 8 + p];
    float M = fmaxf(m, m2);
    s = s * expf(m - M) + s2 * expf(m2 - M);
    m = M;
  }
  colL[i] = m + logf(s);
}

__global__ void sink_col3_kernel(float* __restrict__ S, const float* __restrict__ colL) {
  int b = blockIdx.x / NP1, r = blockIdx.x % NP1;
  float* row = S + ((size_t)b * NP1 + r) * NP1;
  const float* L = colL + (size_t)b * NP;
  for (int c = threadIdx.x; c < NP; c += 256) row[c] -= L[c];
}

// ---------------------------------------------------------------- perm/perm_norm/weights/weighted_tgt
__global__ void perm_kernel(const float* __restrict__ S, const float* __restrict__ tgt,
                            float* __restrict__ outp, float* __restrict__ weights,
                            float* __restrict__ wt) {
  int b = blockIdx.x / NP, n = blockIdx.x % NP, t = threadIdx.x;
  const float* row = S + ((size_t)b * NP1 + n) * NP1;
  __shared__ float e[NP];
  __shared__ float reds[256], redm[256];
  float lm = -INFINITY, lsum = 0.f;
  for (int c = t; c < NP; c += 256) {
    float v = expf(row[c]);
    e[c] = v; lsum += v; lm = fmaxf(lm, v);
  }
  reds[t] = lsum; redm[t] = lm;
  __syncthreads();
  for (int st = 128; st > 0; st >>= 1) {
    if (t < st) { reds[t] += reds[t + st]; redm[t] = fmaxf(redm[t], redm[t + st]); }
    __syncthreads();
  }
  float inv = 1.f / (reds[0] + 1e-8f);
  float mx = redm[0];
  __syncthreads();
  const float* tb = tgt + (size_t)b * 3 * NP;
  float* op = outp + ((size_t)b * NP + n) * NP;
  float a0 = 0.f, a1 = 0.f, a2 = 0.f;
  for (int c = t; c < NP; c += 256) {
    float pn = e[c] * inv;
    op[c] = pn;
    a0 = fmaf(tb[c], pn, a0);
    a1 = fmaf(tb[NP + c], pn, a1);
    a2 = fmaf(tb[2 * NP + c], pn, a2);
  }
  float av[3] = {a0, a1, a2};
  for (int d = 0; d < 3; ++d) {
    reds[t] = av[d];
    __syncthreads();
    for (int st = 128; st > 0; st >>= 1) { if (t < st) reds[t] += reds[t + st]; __syncthreads(); }
    if (t == 0) wt[((size_t)b * 3 + d) * NP + n] = reds[0];
    __syncthreads();
  }
  if (t == 0) weights[(size_t)b * NP + n] = mx;
}

__global__ void wsum_kernel(const float* __restrict__ weights, float* __restrict__ wsum) {
  int b = blockIdx.x, t = threadIdx.x;
  __shared__ float red[256];
  float s = 0.f;
  for (int n = t; n < NP; n += 256) s += weights[(size_t)b * NP + n];
  red[t] = s;
  __syncthreads();
  for (int st = 128; st > 0; st >>= 1) { if (t < st) red[t] += red[t + st]; __syncthreads(); }
  if (t == 0) wsum[b] = red[0];
}

__global__ void cent_hm_kernel(const float* __restrict__ src, const float* __restrict__ wt,
                               const float* __restrict__ weights, const float* __restrict__ wsum,
                               float* __restrict__ cent, float* __restrict__ Hm) {
  int b = blockIdx.x, t = threadIdx.x;
  __shared__ float red[256];
  __shared__ float cc[6];
  float inv = 1.f / (wsum[b] + 1e-8f);
  const float* sb = src + (size_t)b * 3 * NP;
  const float* wb = wt + (size_t)b * 3 * NP;
  const float* ww = weights + (size_t)b * NP;
  float acc[6] = {};
  for (int n = t; n < NP; n += 256) {
    float w = ww[n] * inv;
    acc[0] += sb[n] * w;        acc[1] += sb[NP + n] * w;  acc[2] += sb[2 * NP + n] * w;
    acc[3] += wb[n] * w;        acc[4] += wb[NP + n] * w;  acc[5] += wb[2 * NP + n] * w;
  }
  for (int i = 0; i < 6; ++i) {
    red[t] = acc[i];
    __syncthreads();
    for (int st = 128; st > 0; st >>= 1) { if (t < st) red[t] += red[t + st]; __syncthreads(); }
    if (t == 0) cc[i] = red[0];
    __syncthreads();
  }
  float h[9] = {};
  for (int n = t; n < NP; n += 256) {
    float w = ww[n] * inv;
    float s0 = sb[n] - cc[0], s1 = sb[NP + n] - cc[1], s2 = sb[2 * NP + n] - cc[2];
    float d0 = (wb[n] - cc[3]) * w, d1 = (wb[NP + n] - cc[4]) * w, d2 = (wb[2 * NP + n] - cc[5]) * w;
    h[0] += s0 * d0; h[1] += s0 * d1; h[2] += s0 * d2;
    h[3] += s1 * d0; h[4] += s1 * d1; h[5] += s1 * d2;
    h[6] += s2 * d0; h[7] += s2 * d1; h[8] += s2 * d2;
  }
  for (int i = 0; i < 9; ++i) {
    red[t] = h[i];
    __syncthreads();
    for (int st = 128; st > 0; st >>= 1) { if (t < st) red[t] += red[t + st]; __syncthreads(); }
    if (t == 0) Hm[b * 9 + i] = red[0];
    __syncthreads();
  }
  if (t == 0) for (int i = 0; i < 6; ++i) cent[b * 6 + i] = cc[i];
}

// ---------------------------------------------------------------- 3x3 Kabsch via Jacobi SVD (fp64)
__device__ double det3d(const double M[3][3]) {
  return M[0][0] * (M[1][1] * M[2][2] - M[1][2] * M[2][1])
       - M[0][1] * (M[1][0] * M[2][2] - M[1][2] * M[2][0])
       + M[0][2] * (M[1][0] * M[2][1] - M[1][1] * M[2][0]);
}

__global__ void solve_kernel(const float* __restrict__ Hm, const float* __restrict__ cent,
                             float* __restrict__ out) {
  int b = threadIdx.x;
  if (b >= BATCH) return;
  double A[3][3];
  for (int r = 0; r < 3; ++r)
    for (int c = 0; c < 3; ++c) A[r][c] = (double)Hm[b * 9 + r * 3 + c];
  double S[3][3];
  for (int i = 0; i < 3; ++i)
    for (int j = 0; j < 3; ++j) {
      double acc = 0.0;
      for (int k = 0; k < 3; ++k) acc += A[k][i] * A[k][j];
      S[i][j] = acc;
    }
  double V[3][3] = {{1, 0, 0}, {0, 1, 0}, {0, 0, 1}};
  const int PP[3] = {0, 0, 1}, QQ[3] = {1, 2, 2};
  for (int sweep = 0; sweep < 40; ++sweep) {
    for (int pi = 0; pi < 3; ++pi) {
      int p = PP[pi], q = QQ[pi];
      double apq = S[p][q];
      if (fabs(apq) < 1e-300) continue;
      double tau = (S[q][q] - S[p][p]) / (2.0 * apq);
      double tt = (tau >= 0.0) ? 1.0 / (tau + sqrt(1.0 + tau * tau))
                               : 1.0 / (tau - sqrt(1.0 + tau * tau));
      double c = 1.0 / sqrt(1.0 + tt * tt), s = tt * c;
      for (int k = 0; k < 3; ++k) {
        double skp = S[k][p], skq = S[k][q];
        S[k][p] = c * skp - s * skq;
        S[k][q] = s * skp + c * skq;
      }
      for (int k = 0; k < 3; ++k) {
        double spk = S[p][k], sqk = S[q][k];
        S[p][k] = c * spk - s * sqk;
        S[q][k] = s * spk + c * sqk;
      }
      for (int k = 0; k < 3; ++k) {
        double vkp = V[k][p], vkq = V[k][q];
        V[k][p] = c * vkp - s * vkq;
        V[k][q] = s * vkp + c * vkq;
      }
    }
  }
  double ev[3] = {S[0][0], S[1][1], S[2][2]};
  int ord[3] = {0, 1, 2};
  for (int i = 0; i < 2; ++i)
    for (int j = i + 1; j < 3; ++j)
      if (ev[ord[j]] > ev[ord[i]]) { int tmp = ord[i]; ord[i] = ord[j]; ord[j] = tmp; }
  double Vv[3][3], Us[3][3];
  for (int i = 0; i < 3; ++i)
    for (int r = 0; r < 3; ++r) Vv[r][i] = V[r][ord[i]];
  for (int i = 0; i < 3; ++i) {
    double v0 = Vv[0][i], v1 = Vv[1][i], v2 = Vv[2][i];
    double u0 = A[0][0] * v0 + A[0][1] * v1 + A[0][2] * v2;
    double u1 = A[1][0] * v0 + A[1][1] * v1 + A[1][2] * v2;
    double u2 = A[2][0] * v0 + A[2][1] * v1 + A[2][2] * v2;
    double nrm = sqrt(u0 * u0 + u1 * u1 + u2 * u2);
    if (nrm > 1e-30) { u0 /= nrm; u1 /= nrm; u2 /= nrm; }
    else if (i == 2) { // orthonormal completion (R is invariant to its sign)
      u0 = Us[1][0] * Us[2][1] - Us[2][0] * Us[1][1];
      u1 = Us[2][0] * Us[0][1] - Us[0][0] * Us[2][1];
      u2 = Us[0][0] * Us[1][1] - Us[1][0] * Us[0][1];
      double nn = sqrt(u0 * u0 + u1 * u1 + u2 * u2);
      if (nn > 1e-30) { u0 /= nn; u1 /= nn; u2 /= nn; }
    }
    Us[0][i] = u0; Us[1][i] = u1; Us[2][i] = u2;
  }
  double d = det3d(Vv) * det3d(Us);
  double R[3][3];
  for (int i = 0; i < 3; ++i)
    for (int j = 0; j < 3; ++j)
      R[i][j] = Vv[i][0] * Us[j][0] + Vv[i][1] * Us[j][1] + d * Vv[i][2] * Us[j][2];
  double sc[3] = {(double)cent[b * 6 + 0], (double)cent[b * 6 + 1], (double)cent[b * 6 + 2]};
  double tc[3] = {(double)cent[b * 6 + 3], (double)cent[b * 6 + 4], (double)cent[b * 6 + 5]};
  for (int r = 0; r < 3; ++r)
    for (int c = 0; c < 3; ++c) out[b * 9 + r * 3 + c] = (float)R[r][c];
  for (int i = 0; i < 3; ++i) {
    double tv = tc[i] - (R[i][0] * sc[0] + R[i][1] * sc[1] + R[i][2] * sc[2]);
    out[36 + b * 3 + i] = (float)tv;
  }
}

// ---------------------------------------------------------------- launch
extern "C" void kernel_launch(void* const* d_in, const int* in_sizes, int n_in,
                              void* d_out, int out_size, void* d_ws, size_t ws_size,
                              hipStream_t stream) {
  const float* src  = (const float*)d_in[0];
  const float* tgt  = (const float*)d_in[1];
  const float* g_w1 = (const float*)d_in[2];
  const float* g_s1 = (const float*)d_in[3];
  const float* g_b1 = (const float*)d_in[4];
  const float* g_w2 = (const float*)d_in[5];
  const float* g_s2 = (const float*)d_in[6];
  const float* g_b2 = (const float*)d_in[7];
  const float* g_wo = (const float*)d_in[8];
  const float* g_so = (const float*)d_in[9];
  const float* g_bo = (const float*)d_in[10];
  const float* q_w  = (const float*)d_in[11];
  const float* q_b  = (const float*)d_in[12];
  const float* k_w  = (const float*)d_in[13];
  const float* k_b  = (const float*)d_in[14];
  const float* v_w  = (const float*)d_in[15];
  const float* v_b  = (const float*)d_in[16];
  const float* m_w  = (const float*)d_in[17];
  const float* m_b  = (const float*)d_in[18];
  const float* mlp_w = (const float*)d_in[19];
  float* out = (float*)d_out;
  float* ws = (float*)d_ws;

  const size_t SLOT = 4194304; // 512*2048*4 batches of floats (16 MB)
  float* d0   = ws + 0 * SLOT;
  float* d1   = ws + 1 * SLOT;
  float* Q0   = ws + 2 * SLOT;
  float* K0   = ws + 3 * SLOT;
  float* V0   = ws + 4 * SLOT;
  float* Q1   = ws + 5 * SLOT;
  float* K1   = ws + 6 * SLOT;
  float* V1   = ws + 7 * SLOT;
  float* att0 = ws + 8 * SLOT;
  float* att1 = ws + 9 * SLOT;
  float* mp0 = Q0;   // Q0 dead after attention
  float* mp1 = Q1;   // Q1 dead after attention
  float* d0n = att0; // att0 dead after m-proj
  float* d1n = att1;
  float* Sb = ws;    // sinkhorn buffer overlaps d0..V0 (all dead by dists time)
  // smalls live in slot 5 (idx used pre-proj; the rest used post-mlp)
  int*   idx0 = (int*)(ws + 5 * SLOT);
  int*   idx1 = idx0 + BATCH * NP * KNNK;
  float* colM = ws + 5 * SLOT + 327680;
  float* colS = colM + BATCH * NP * 8;
  float* colL = colS + BATCH * NP * 8;
  float* weights = colL + BATCH * NP;
  float* wsum = weights + BATCH * NP;
  float* wtg  = wsum + BATCH;
  float* cent = wtg + BATCH * 3 * NP;
  float* Hmb  = cent + BATCH * 6;

  // 1. kNN
  knn_kernel<<<BATCH * NP, 256, 0, stream>>>(src, idx0);
  knn_kernel<<<BATCH * NP, 256, 0, stream>>>(tgt, idx1);
  // 2. GAC
  gac_kernel<<<BATCH * NP, 256, 0, stream>>>(src, idx0, g_w1, g_s1, g_b1, g_w2, g_s2, g_b2,
                                             g_wo, g_so, g_bo, d0);
  gac_kernel<<<BATCH * NP, 256, 0, stream>>>(tgt, idx1, g_w1, g_s1, g_b1, g_w2, g_s2, g_b2,
                                             g_wo, g_so, g_bo, d1);
  // 3. Q/K/V projections (head-split layout)
  dim3 gp(NP / 64, DEMB / 64, BATCH);
  gemm_bias_kernel<1><<<gp, 256, 0, stream>>>(q_w, q_b, d0, Q0, DEMB);
  gemm_bias_kernel<1><<<gp, 256, 0, stream>>>(k_w, k_b, d0, K0, DEMB);
  gemm_bias_kernel<1><<<gp, 256, 0, stream>>>(v_w, v_b, d0, V0, DEMB);
  gemm_bias_kernel<1><<<gp, 256, 0, stream>>>(q_w, q_b, d1, Q1, DEMB);
  gemm_bias_kernel<1><<<gp, 256, 0, stream>>>(k_w, k_b, d1, K1, DEMB);
  gemm_bias_kernel<1><<<gp, 256, 0, stream>>>(v_w, v_b, d1, V1, DEMB);
  // 4. cross attention
  attn_kernel<<<BATCH * NH * (NP / 32), 256, 0, stream>>>(Q0, K1, V1, att0);
  attn_kernel<<<BATCH * NH * (NP / 32), 256, 0, stream>>>(Q1, K0, V0, att1);
  // 5. message projection
  gemm_bias_kernel<0><<<gp, 256, 0, stream>>>(m_w, m_b, att0, mp0, DEMB);
  gemm_bias_kernel<0><<<gp, 256, 0, stream>>>(m_w, m_b, att1, mp1, DEMB);
  // 6. MLP + residual
  gemm_mlp_kernel<<<gp, 256, 0, stream>>>(mlp_w, d0, mp0, d0, d0n);
  gemm_mlp_kernel<<<gp, 256, 0, stream>>>(mlp_w, d1, mp1, d1, d1n);
  // 7. dists into padded sinkhorn buffer
  dim3 gd(NP / 64, NP / 64, BATCH);
  dists_kernel<<<gd, 256, 0, stream>>>(d0n, d1n, Sb);
  sink_pad_kernel<<<(BATCH * NP1 + 255) / 256, 256, 0, stream>>>(Sb);
  // 8. sinkhorn, 5 iterations
  for (int it = 0; it < 5; ++it) {
    sink_row_kernel<<<BATCH * NP, 256, 0, stream>>>(Sb);
    sink_col1_kernel<<<dim3(NP / 64, 8, BATCH), 256, 0, stream>>>(Sb, colM, colS);
    sink_col2_kernel<<<(BATCH * NP + 255) / 256, 256, 0, stream>>>(colM, colS, colL);
    sink_col3_kernel<<<BATCH * NP1, 256, 0, stream>>>(Sb, colL);
  }
  // 9. perm_norm (to out) + weights + weighted_tgt
  perm_kernel<<<BATCH * NP, 256, 0, stream>>>(Sb, tgt, out + 48, weights, wtg);
  // 10. Kabsch
  wsum_kernel<<<BATCH, 256, 0, stream>>>(weights, wsum);
  cent_hm_kernel<<<BATCH, 256, 0, stream>>>(src, wtg, weights, wsum, cent, Hmb);
  solve_kernel<<<1, 64, 0, stream>>>(Hmb, cent, out);
}

// Round 2
// 3667.237 us; speedup vs baseline: 1.7310x; 1.7310x over previous
//
#include <hip/hip_runtime.h>
#include <math.h>

#define BATCH 4
#define NP    2048
#define NP1   2049
#define KNNK  20
#define DEMB  512
#define NH    4
#define DHD   128

typedef __attribute__((ext_vector_type(8))) short bf16x8;
typedef __attribute__((ext_vector_type(4))) float f32x4;
typedef unsigned short ushortx;

__device__ __forceinline__ unsigned short f2b(float f) {
  unsigned u = __builtin_bit_cast(unsigned, f);
  u += 0x7FFF + ((u >> 16) & 1);
  return (unsigned short)(u >> 16);
}

__device__ __forceinline__ void gload_lds16(const void* g, void* l) {
  __builtin_amdgcn_global_load_lds(
      (const __attribute__((address_space(1))) unsigned int*)g,
      (__attribute__((address_space(3))) unsigned int*)l, 16, 0, 0);
}

// ---------------------------------------------------------------- kNN top-20
__global__ void knn_kernel(const float* __restrict__ x, int* __restrict__ idx_out) {
  int b = blockIdx.x / NP, n = blockIdx.x % NP, t = threadIdx.x;
  __shared__ float xs0[NP], xs1[NP], xs2[NP];
  __shared__ float nd[NP];
  __shared__ float rv[256];
  __shared__ int   ri[256];
  const float* xb = x + (size_t)b * 3 * NP;
  for (int m = t; m < NP; m += 256) {
    xs0[m] = xb[m]; xs1[m] = xb[NP + m]; xs2[m] = xb[2 * NP + m];
  }
  __syncthreads();
  float c0 = xs0[n], c1 = xs1[n], c2 = xs2[n];
  float xxn = c0 * c0 + c1 * c1 + c2 * c2;
  for (int m = t; m < NP; m += 256) {
    float a0 = xs0[m], a1 = xs1[m], a2 = xs2[m];
    float inner = c0 * a0 + c1 * a1 + c2 * a2;
    float xxm = a0 * a0 + a1 * a1 + a2 * a2;
    nd[m] = 2.f * inner - xxn - xxm;
  }
  __syncthreads();
  int* orow = idx_out + ((size_t)b * NP + n) * KNNK;
  for (int it = 0; it < KNNK; ++it) {
    float bv = -INFINITY; int bi = -1;
    for (int m = t; m < NP; m += 256) {
      float v = nd[m];
      if (v > bv || (v == bv && m < bi)) { bv = v; bi = m; }
    }
    rv[t] = bv; ri[t] = bi;
    __syncthreads();
    for (int s = 128; s > 0; s >>= 1) {
      if (t < s) {
        float ov = rv[t + s]; int oi = ri[t + s];
        if (ov > rv[t] || (ov == rv[t] && oi < ri[t])) { rv[t] = ov; ri[t] = oi; }
      }
      __syncthreads();
    }
    if (t == 0) { orow[it] = ri[0]; nd[ri[0]] = -INFINITY; }
    __syncthreads();
  }
}

// ---------------------------------------------------------------- fused GAC (one block per point)
__global__ void gac_kernel(const float* __restrict__ x, const int* __restrict__ idx,
                           const float* __restrict__ w1, const float* __restrict__ s1, const float* __restrict__ b1,
                           const float* __restrict__ w2, const float* __restrict__ s2, const float* __restrict__ b2,
                           const float* __restrict__ wo, const float* __restrict__ so, const float* __restrict__ bo,
                           float* __restrict__ dout) {
  int b = blockIdx.x / NP, n = blockIdx.x % NP, t = threadIdx.x;
  __shared__ float g[6][KNNK];
  __shared__ float h1[64][KNNK + 1];
  __shared__ float h2[128][KNNK + 1];
  __shared__ float xc[192];
  __shared__ float w1s[64 * 6];
  __shared__ float w2s[128 * 64];
  for (int i = t; i < 64 * 6; i += 256)  w1s[i] = w1[i];
  for (int i = t; i < 128 * 64; i += 256) w2s[i] = w2[i];
  const float* xb = x + (size_t)b * 3 * NP;
  if (t < KNNK) {
    int j = idx[((size_t)b * NP + n) * KNNK + t];
    float c0 = xb[n], c1 = xb[NP + n], c2 = xb[2 * NP + n];
    float f0 = xb[j], f1 = xb[NP + j], f2 = xb[2 * NP + j];
    g[0][t] = f0 - c0; g[1][t] = f1 - c1; g[2][t] = f2 - c2;
    g[3][t] = c0; g[4][t] = c1; g[5][t] = c2;
  }
  __syncthreads();
  for (int item = t; item < 64 * KNNK; item += 256) {
    int o = item / KNNK, k = item % KNNK;
    float y = 0.f;
#pragma unroll
    for (int c = 0; c < 6; ++c) y += w1s[o * 6 + c] * g[c][k];
    y = y * s1[o] + b1[o];
    h1[o][k] = fmaxf(y, 0.f);
  }
  __syncthreads();
  if (t < 64) {
    float mx = -INFINITY;
    for (int k = 0; k < KNNK; ++k) mx = fmaxf(mx, h1[t][k]);
    float se = 0.f, sh = 0.f;
    for (int k = 0; k < KNNK; ++k) { float e = expf(h1[t][k] - mx); se += e; sh += h1[t][k] * e; }
    xc[t] = sh / se;
  }
  __syncthreads();
  for (int item = t; item < 128 * KNNK; item += 256) {
    int o = item / KNNK, k = item % KNNK;
    float y = 0.f;
    for (int c = 0; c < 64; ++c) y += w2s[o * 64 + c] * h1[c][k];
    y = y * s2[o] + b2[o];
    h2[o][k] = fmaxf(y, 0.f);
  }
  __syncthreads();
  if (t < 128) {
    float mx = -INFINITY;
    for (int k = 0; k < KNNK; ++k) mx = fmaxf(mx, h2[t][k]);
    float se = 0.f, sh = 0.f;
    for (int k = 0; k < KNNK; ++k) { float e = expf(h2[t][k] - mx); se += e; sh += h2[t][k] * e; }
    xc[64 + t] = sh / se;
  }
  __syncthreads();
  for (int o = t; o < DEMB; o += 256) {
    float y = 0.f;
    for (int c = 0; c < 192; ++c) y += wo[o * 192 + c] * xc[c];
    y = y * so[o] + bo[o];
    dout[((size_t)b * DEMB + o) * NP + n] = fmaxf(y, 0.f);
  }
}

// ---------------------------------------------------------------- GEMM: Y = W(512xC) @ X(B,C,N) + bias
// MODE 0: f32 (B,512,N); MODE 1: f32 (B,H,N,DH); MODE 2: bf16 (B,H,N,DH); MODE 3: bf16 (B,H,DH,N)
template <int MODE>
__global__ void gemm_bias_kernel(const float* __restrict__ W, const float* __restrict__ bias,
                                 const float* __restrict__ X, void* __restrict__ Yv, int C) {
  int n0 = blockIdx.x * 64, o0 = blockIdx.y * 64, b = blockIdx.z;
  int t = threadIdx.x, tx = t & 15, ty = t >> 4;
  __shared__ float Ws[16][65];
  __shared__ float Xs[16][65];
  float acc[4][4] = {};
  const float* Xb = X + (size_t)b * C * NP;
  for (int k0 = 0; k0 < C; k0 += 16) {
#pragma unroll
    for (int u = 0; u < 4; ++u) {
      int li = t + 256 * u;
      int i = li >> 4, j = li & 15;
      Ws[j][i] = W[(size_t)(o0 + i) * C + k0 + j];
      int i2 = li & 63, j2 = li >> 6;
      Xs[j2][i2] = Xb[(size_t)(k0 + j2) * NP + n0 + i2];
    }
    __syncthreads();
#pragma unroll
    for (int k = 0; k < 16; ++k) {
      float a[4], bb[4];
#pragma unroll
      for (int ii = 0; ii < 4; ++ii) a[ii] = Ws[k][ty + 16 * ii];
#pragma unroll
      for (int jj = 0; jj < 4; ++jj) bb[jj] = Xs[k][tx + 16 * jj];
#pragma unroll
      for (int ii = 0; ii < 4; ++ii)
#pragma unroll
        for (int jj = 0; jj < 4; ++jj) acc[ii][jj] += a[ii] * bb[jj];
    }
    __syncthreads();
  }
#pragma unroll
  for (int ii = 0; ii < 4; ++ii) {
    int o = o0 + ty + 16 * ii;
    float bv = bias[o];
#pragma unroll
    for (int jj = 0; jj < 4; ++jj) {
      int n = n0 + tx + 16 * jj;
      float v = acc[ii][jj] + bv;
      int h = o & 3, dh = o >> 2;
      if (MODE == 0) {
        ((float*)Yv)[((size_t)b * DEMB + o) * NP + n] = v;
      } else if (MODE == 1) {
        ((float*)Yv)[(((size_t)b * NH + h) * NP + n) * DHD + dh] = v;
      } else if (MODE == 2) {
        ((unsigned short*)Yv)[(((size_t)b * NH + h) * NP + n) * DHD + dh] = f2b(v);
      } else {
        ((unsigned short*)Yv)[(((size_t)b * NH + h) * DHD + dh) * NP + n] = f2b(v);
      }
    }
  }
}

// ---------------------------------------------------------------- MLP: Y = D + W(512x1024) @ [Xa;Xb]
__global__ void gemm_mlp_kernel(const float* __restrict__ W, const float* __restrict__ Xa,
                                const float* __restrict__ Xb, const float* __restrict__ D,
                                float* __restrict__ Y) {
  int n0 = blockIdx.x * 64, o0 = blockIdx.y * 64, b = blockIdx.z;
  int t = threadIdx.x, tx = t & 15, ty = t >> 4;
  __shared__ float Ws[16][65];
  __shared__ float Xs[16][65];
  float acc[4][4] = {};
  const float* Xab = Xa + (size_t)b * DEMB * NP;
  const float* Xbb = Xb + (size_t)b * DEMB * NP;
  for (int k0 = 0; k0 < 1024; k0 += 16) {
    const float* src = (k0 < 512) ? (Xab + (size_t)k0 * NP) : (Xbb + (size_t)(k0 - 512) * NP);
#pragma unroll
    for (int u = 0; u < 4; ++u) {
      int li = t + 256 * u;
      int i = li >> 4, j = li & 15;
      Ws[j][i] = W[(size_t)(o0 + i) * 1024 + k0 + j];
      int i2 = li & 63, j2 = li >> 6;
      Xs[j2][i2] = src[(size_t)j2 * NP + n0 + i2];
    }
    __syncthreads();
#pragma unroll
    for (int k = 0; k < 16; ++k) {
      float a[4], bb[4];
#pragma unroll
      for (int ii = 0; ii < 4; ++ii) a[ii] = Ws[k][ty + 16 * ii];
#pragma unroll
      for (int jj = 0; jj < 4; ++jj) bb[jj] = Xs[k][tx + 16 * jj];
#pragma unroll
      for (int ii = 0; ii < 4; ++ii)
#pragma unroll
        for (int jj = 0; jj < 4; ++jj) acc[ii][jj] += a[ii] * bb[jj];
    }
    __syncthreads();
  }
#pragma unroll
  for (int ii = 0; ii < 4; ++ii) {
    int o = o0 + ty + 16 * ii;
#pragma unroll
    for (int jj = 0; jj < 4; ++jj) {
      int n = n0 + tx + 16 * jj;
      size_t oi = ((size_t)b * DEMB + o) * NP + n;
      Y[oi] = acc[ii][jj] + D[oi];
    }
  }
}

// ---------------------------------------------------------------- MFMA flash attention
// Q: f32 (B,H,N,DH); K: bf16 (B,H,N,DH); V: bf16 (B,H,DH,N); att out: f32 (B,512,N)
// Block: 4 waves x 16 queries = 64 q. Grid: 16 bh * 32 qtiles.
__global__ __launch_bounds__(256, 3) void attn_mfma_kernel(
    const float* __restrict__ Q, const unsigned short* __restrict__ Kb,
    const unsigned short* __restrict__ Vb, float* __restrict__ att) {
  __shared__ unsigned short Klds[8192];  // 16KB: [64 key][128 kd] swizzled
  __shared__ unsigned short Vlds[8192];  // 16KB: [128 d][64 key] swizzled
  __shared__ float Pws[4][544];          // per-wave: P bf16 [16][64] swz / out-stage [16][33] f32

  int bh = blockIdx.x >> 5, qt = blockIdx.x & 31;
  int tid = threadIdx.x;
  int w = tid >> 6, lane = tid & 63;
  int lr = lane & 15, lg = lane >> 4;
  int q0 = qt * 64 + w * 16;

  // Q fragments (A-layout: row=lane&15, kd = 8*lg + 32*dstep)
  const float* Qrow = Q + ((size_t)bh * NP + q0 + lr) * DHD + lg * 8;
  bf16x8 qf[4];
#pragma unroll
  for (int ds = 0; ds < 4; ++ds) {
    float4 x0 = *(const float4*)(Qrow + ds * 32);
    float4 x1 = *(const float4*)(Qrow + ds * 32 + 4);
    bf16x8 v;
    v[0] = (short)f2b(x0.x); v[1] = (short)f2b(x0.y);
    v[2] = (short)f2b(x0.z); v[3] = (short)f2b(x0.w);
    v[4] = (short)f2b(x1.x); v[5] = (short)f2b(x1.y);
    v[6] = (short)f2b(x1.z); v[7] = (short)f2b(x1.w);
    qf[ds] = v;
  }

  const unsigned short* Kg = Kb + (size_t)bh * NP * DHD;  // [key][kd]
  const unsigned short* Vg = Vb + (size_t)bh * DHD * NP;  // [d][n]
  unsigned short* Pl = (unsigned short*)&Pws[w][0];

  f32x4 o[8];
#pragma unroll
  for (int ds = 0; ds < 8; ++ds) o[ds] = (f32x4){0.f, 0.f, 0.f, 0.f};
  float mrun[4] = {-INFINITY, -INFINITY, -INFINITY, -INFINITY};
  float lrun[4] = {0.f, 0.f, 0.f, 0.f};
  const float scale = 0.08838834764831845f;  // 1/sqrt(128)

  for (int kv0 = 0; kv0 < NP; kv0 += 64) {
    __syncthreads();  // previous tile fully consumed
#pragma unroll
    for (int u = 0; u < 4; ++u) {
      int C = (w * 4 + u) * 64 + lane;
      int key = C >> 4, jl = C & 15, j = jl ^ (key & 7);
      gload_lds16(Kg + (size_t)(kv0 + key) * DHD + j * 8, Klds + (w * 4 + u) * 512);
      int d = C >> 3, jv = (C & 7) ^ (d & 7);
      gload_lds16(Vg + (size_t)d * NP + kv0 + jv * 8, Vlds + (w * 4 + u) * 512);
    }
    asm volatile("s_waitcnt vmcnt(0)" ::: "memory");
    __syncthreads();

    // scores: 16q x 64k
    f32x4 s[4];
#pragma unroll
    for (int ks = 0; ks < 4; ++ks) {
      s[ks] = (f32x4){0.f, 0.f, 0.f, 0.f};
      int key = ks * 16 + lr;
#pragma unroll
      for (int dstep = 0; dstep < 4; ++dstep) {
        int dbyte = (lg * 16 + dstep * 64) ^ ((key & 7) << 4);
        bf16x8 kb = *(const bf16x8*)(Klds + key * 128 + (dbyte >> 1));
        s[ks] = __builtin_amdgcn_mfma_f32_16x16x32_bf16(qf[dstep], kb, s[ks], 0, 0, 0);
      }
    }
    // online softmax (rows: q = lg*4 + r; cols: key = ks*16 + lr)
    float tmax[4];
#pragma unroll
    for (int r = 0; r < 4; ++r) {
      float m = -INFINITY;
#pragma unroll
      for (int ks = 0; ks < 4; ++ks) { s[ks][r] *= scale; m = fmaxf(m, s[ks][r]); }
#pragma unroll
      for (int msk = 1; msk < 16; msk <<= 1) m = fmaxf(m, __shfl_xor(m, msk));
      tmax[r] = m;
    }
    float fac[4], ps[4];
#pragma unroll
    for (int r = 0; r < 4; ++r) {
      float mnew = fmaxf(mrun[r], tmax[r]);
      fac[r] = __expf(mrun[r] - mnew);
      mrun[r] = mnew;
      ps[r] = 0.f;
    }
#pragma unroll
    for (int ks = 0; ks < 4; ++ks) {
      int k = ks * 16 + lr;
#pragma unroll
      for (int r = 0; r < 4; ++r) {
        float p = __expf(s[ks][r] - mrun[r]);
        ps[r] += p;
        int q = lg * 4 + r;
        int kbyte = (k * 2) ^ ((q & 7) << 4);
        Pl[q * 64 + (kbyte >> 1)] = f2b(p);
      }
    }
#pragma unroll
    for (int r = 0; r < 4; ++r) {
#pragma unroll
      for (int msk = 1; msk < 16; msk <<= 1) ps[r] += __shfl_xor(ps[r], msk);
      lrun[r] = lrun[r] * fac[r] + ps[r];
    }
#pragma unroll
    for (int ds = 0; ds < 8; ++ds)
#pragma unroll
      for (int r = 0; r < 4; ++r) o[ds][r] *= fac[r];
    // PV: out += P(16x64) @ V(64x128)
#pragma unroll
    for (int ks2 = 0; ks2 < 2; ++ks2) {
      int kbyte = ((lg * 8 + ks2 * 32) * 2) ^ ((lr & 7) << 4);
      bf16x8 pa = *(const bf16x8*)(Pl + lr * 64 + (kbyte >> 1));
#pragma unroll
      for (int ds = 0; ds < 8; ++ds) {
        int d = ds * 16 + lr;
        int keybyte = ((lg * 8 + ks2 * 32) * 2) ^ ((d & 7) << 4);
        bf16x8 vb = *(const bf16x8*)(Vlds + d * 64 + (keybyte >> 1));
        o[ds] = __builtin_amdgcn_mfma_f32_16x16x32_bf16(pa, vb, o[ds], 0, 0, 0);
      }
    }
  }

  // epilogue: normalize and write coalesced via per-wave LDS staging
  float linv[4];
#pragma unroll
  for (int r = 0; r < 4; ++r) linv[r] = 1.f / lrun[r];
  float* ost = &Pws[w][0];
  int b = bh >> 2, h = bh & 3;
#pragma unroll
  for (int c = 0; c < 4; ++c) {
#pragma unroll
    for (int half = 0; half < 2; ++half) {
      int ds = 2 * c + half;
#pragma unroll
      for (int r = 0; r < 4; ++r)
        ost[(lg * 4 + r) * 33 + half * 16 + lr] = o[ds][r] * linv[r];
    }
#pragma unroll
    for (int it = 0; it < 8; ++it) {
      int q = lr, dl = it * 4 + lg;
      float val = ost[q * 33 + dl];
      int d = c * 32 + dl;
      att[((size_t)b * DEMB + d * 4 + h) * NP + qt * 64 + w * 16 + q] = val;
    }
    __syncthreads();  // keep waves loosely in step; also orders ost reuse
  }
}

// ---------------------------------------------------------------- dists -> padded sinkhorn buffer
__global__ void dists_kernel(const float* __restrict__ A, const float* __restrict__ Bm,
                             float* __restrict__ S) {
  int m0 = blockIdx.x * 64, n0 = blockIdx.y * 64, b = blockIdx.z;
  int t = threadIdx.x, tx = t & 15, ty = t >> 4;
  __shared__ float As[16][65];
  __shared__ float Bs[16][65];
  float acc[4][4] = {};
  const float* Ab = A + (size_t)b * DEMB * NP;
  const float* Bb = Bm + (size_t)b * DEMB * NP;
  for (int k0 = 0; k0 < DEMB; k0 += 16) {
#pragma unroll
    for (int u = 0; u < 4; ++u) {
      int li = t + 256 * u;
      int i2 = li & 63, j2 = li >> 6;
      As[j2][i2] = Ab[(size_t)(k0 + j2) * NP + n0 + i2];
      Bs[j2][i2] = Bb[(size_t)(k0 + j2) * NP + m0 + i2];
    }
    __syncthreads();
#pragma unroll
    for (int k = 0; k < 16; ++k) {
      float a[4], bb[4];
#pragma unroll
      for (int ii = 0; ii < 4; ++ii) a[ii] = As[k][ty + 16 * ii];
#pragma unroll
      for (int jj = 0; jj < 4; ++jj) bb[jj] = Bs[k][tx + 16 * jj];
#pragma unroll
      for (int ii = 0; ii < 4; ++ii)
#pragma unroll
        for (int jj = 0; jj < 4; ++jj) acc[ii][jj] += a[ii] * bb[jj];
    }
    __syncthreads();
  }
  const float scale = 0.04419417382415922f;  // 1/sqrt(512)
#pragma unroll
  for (int ii = 0; ii < 4; ++ii) {
    int n = n0 + ty + 16 * ii;
#pragma unroll
    for (int jj = 0; jj < 4; ++jj) {
      int m = m0 + tx + 16 * jj;
      S[(size_t)b * NP1 * NP1 + (size_t)n * NP1 + m] = acc[ii][jj] * scale;
    }
  }
}

__global__ void sink_pad_kernel(float* __restrict__ S) {
  int i = blockIdx.x * 256 + threadIdx.x;
  if (i >= BATCH * NP1) return;
  int b = i / NP1, r = i % NP1;
  S[((size_t)b * NP1 + r) * NP1 + NP] = 0.f;
  S[((size_t)b * NP1 + NP) * NP1 + r] = 0.f;
}

__global__ void sink_row_kernel(float* __restrict__ S) {
  int b = blockIdx.x / NP, r = blockIdx.x % NP, t = threadIdx.x;
  float* row = S + ((size_t)b * NP1 + r) * NP1;
  __shared__ float rm[256], rs[256];
  float m = -INFINITY, s = 0.f;
  for (int c = t; c < NP1; c += 256) {
    float x = row[c];
    float nm = fmaxf(m, x);
    s = s * expf(m - nm) + expf(x - nm);
    m = nm;
  }
  rm[t] = m; rs[t] = s;
  __syncthreads();
  for (int st = 128; st > 0; st >>= 1) {
    if (t < st) {
      float m2 = rm[t + st], s2 = rs[t + st];
      float M = fmaxf(rm[t], m2);
      rs[t] = rs[t] * expf(rm[t] - M) + s2 * expf(m2 - M);
      rm[t] = M;
    }
    __syncthreads();
  }
  float lse = rm[0] + logf(rs[0]);
  for (int c = t; c < NP1; c += 256) row[c] -= lse;
}

__global__ void sink_col1_kernel(const float* __restrict__ S, float* __restrict__ colM,
                                 float* __restrict__ colS) {
  int ctile = blockIdx.x, part = blockIdx.y, b = blockIdx.z;
  int t = threadIdx.x, ry = t >> 6, cx = t & 63;
  int c = ctile * 64 + cx;
  int r0 = part * 256, r1 = (part == 7) ? NP1 : (r0 + 256);
  const float* Sb = S + (size_t)b * NP1 * NP1;
  float m = -INFINITY, s = 0.f;
  for (int r = r0 + ry; r < r1; r += 4) {
    float x = Sb[(size_t)r * NP1 + c];
    float nm = fmaxf(m, x);
    s = s * expf(m - nm) + expf(x - nm);
    m = nm;
  }
  __shared__ float pm[4][64], ps[4][64];
  pm[ry][cx] = m; ps[ry][cx] = s;
  __syncthreads();
  if (ry == 0) {
    for (int k = 1; k < 4; ++k) {
      float m2 = pm[k][cx], s2 = ps[k][cx];
      float M = fmaxf(m, m2);
      s = s * expf(m - M) + s2 * expf(m2 - M);
      m = M;
    }
    size_t oo = ((size_t)b * NP + c) * 8 + part;
    colM[oo] = m; colS[oo] = s;
  }
}

__global__ void sink_col2_kernel(const float* __restrict__ colM, const float* __restrict__ colS,
                                 float* __restrict__ colL) {
  int i = blockIdx.x * 256 + threadIdx.x;
  if (i >= BATCH * NP) return;
  float m = -INFINITY, s = 0.f;
  for (int p = 0; p < 8; ++p) {
    float m2 = colM[(size_t)i * 8 + p], s2 = colS[(size_t)i * 8 + p];
    float M = fmaxf(m, m2);
    s = s * expf(m - M) + s2 * expf(m2 - M);
    m = M;
  }
  colL[i] = m + logf(s);
}

__global__ void sink_col3_kernel(float* __restrict__ S, const float* __restrict__ colL) {
  int b = blockIdx.x / NP1, r = blockIdx.x % NP1;
  float* row = S + ((size_t)b * NP1 + r) * NP1;
  const float* L = colL + (size_t)b * NP;
  for (int c = threadIdx.x; c < NP; c += 256) row[c] -= L[c];
}

// ---------------------------------------------------------------- perm/perm_norm/weights/weighted_tgt
__global__ void perm_kernel(const float* __restrict__ S, const float* __restrict__ tgt,
                            float* __restrict__ outp, float* __restrict__ weights,
                            float* __restrict__ wt) {
  int b = blockIdx.x / NP, n = blockIdx.x % NP, t = threadIdx.x;
  const float* row = S + ((size_t)b * NP1 + n) * NP1;
  __shared__ float e[NP];
  __shared__ float reds[256], redm[256];
  float lm = -INFINITY, lsum = 0.f;
  for (int c = t; c < NP; c += 256) {
    float v = expf(row[c]);
    e[c] = v; lsum += v; lm = fmaxf(lm, v);
  }
  reds[t] = lsum; redm[t] = lm;
  __syncthreads();
  for (int st = 128; st > 0; st >>= 1) {
    if (t < st) { reds[t] += reds[t + st]; redm[t] = fmaxf(redm[t], redm[t + st]); }
    __syncthreads();
  }
  float inv = 1.f / (reds[0] + 1e-8f);
  float mx = redm[0];
  __syncthreads();
  const float* tb = tgt + (size_t)b * 3 * NP;
  float* op = outp + ((size_t)b * NP + n) * NP;
  float a0 = 0.f, a1 = 0.f, a2 = 0.f;
  for (int c = t; c < NP; c += 256) {
    float pn = e[c] * inv;
    op[c] = pn;
    a0 = fmaf(tb[c], pn, a0);
    a1 = fmaf(tb[NP + c], pn, a1);
    a2 = fmaf(tb[2 * NP + c], pn, a2);
  }
  float av[3] = {a0, a1, a2};
  for (int d = 0; d < 3; ++d) {
    reds[t] = av[d];
    __syncthreads();
    for (int st = 128; st > 0; st >>= 1) { if (t < st) reds[t] += reds[t + st]; __syncthreads(); }
    if (t == 0) wt[((size_t)b * 3 + d) * NP + n] = reds[0];
    __syncthreads();
  }
  if (t == 0) weights[(size_t)b * NP + n] = mx;
}

__global__ void wsum_kernel(const float* __restrict__ weights, float* __restrict__ wsum) {
  int b = blockIdx.x, t = threadIdx.x;
  __shared__ float red[256];
  float s = 0.f;
  for (int n = t; n < NP; n += 256) s += weights[(size_t)b * NP + n];
  red[t] = s;
  __syncthreads();
  for (int st = 128; st > 0; st >>= 1) { if (t < st) red[t] += red[t + st]; __syncthreads(); }
  if (t == 0) wsum[b] = red[0];
}

__global__ void cent_hm_kernel(const float* __restrict__ src, const float* __restrict__ wt,
                               const float* __restrict__ weights, const float* __restrict__ wsum,
                               float* __restrict__ cent, float* __restrict__ Hm) {
  int b = blockIdx.x, t = threadIdx.x;
  __shared__ float red[256];
  __shared__ float cc[6];
  float inv = 1.f / (wsum[b] + 1e-8f);
  const float* sb = src + (size_t)b * 3 * NP;
  const float* wb = wt + (size_t)b * 3 * NP;
  const float* ww = weights + (size_t)b * NP;
  float acc[6] = {};
  for (int n = t; n < NP; n += 256) {
    float w = ww[n] * inv;
    acc[0] += sb[n] * w;        acc[1] += sb[NP + n] * w;  acc[2] += sb[2 * NP + n] * w;
    acc[3] += wb[n] * w;        acc[4] += wb[NP + n] * w;  acc[5] += wb[2 * NP + n] * w;
  }
  for (int i = 0; i < 6; ++i) {
    red[t] = acc[i];
    __syncthreads();
    for (int st = 128; st > 0; st >>= 1) { if (t < st) red[t] += red[t + st]; __syncthreads(); }
    if (t == 0) cc[i] = red[0];
    __syncthreads();
  }
  float h[9] = {};
  for (int n = t; n < NP; n += 256) {
    float w = ww[n] * inv;
    float s0 = sb[n] - cc[0], s1 = sb[NP + n] - cc[1], s2 = sb[2 * NP + n] - cc[2];
    float d0 = (wb[n] - cc[3]) * w, d1 = (wb[NP + n] - cc[4]) * w, d2 = (wb[2 * NP + n] - cc[5]) * w;
    h[0] += s0 * d0; h[1] += s0 * d1; h[2] += s0 * d2;
    h[3] += s1 * d0; h[4] += s1 * d1; h[5] += s1 * d2;
    h[6] += s2 * d0; h[7] += s2 * d1; h[8] += s2 * d2;
  }
  for (int i = 0; i < 9; ++i) {
    red[t] = h[i];
    __syncthreads();
    for (int st = 128; st > 0; st >>= 1) { if (t < st) red[t] += red[t + st]; __syncthreads(); }
    if (t == 0) Hm[b * 9 + i] = red[0];
    __syncthreads();
  }
  if (t == 0) for (int i = 0; i < 6; ++i) cent[b * 6 + i] = cc[i];
}

// ---------------------------------------------------------------- 3x3 Kabsch via Jacobi SVD (fp64)
__device__ double det3d(const double M[3][3]) {
  return M[0][0] * (M[1][1] * M[2][2] - M[1][2] * M[2][1])
       - M[0][1] * (M[1][0] * M[2][2] - M[1][2] * M[2][0])
       + M[0][2] * (M[1][0] * M[2][1] - M[1][1] * M[2][0]);
}

__global__ void solve_kernel(const float* __restrict__ Hm, const float* __restrict__ cent,
                             float* __restrict__ out) {
  int b = threadIdx.x;
  if (b >= BATCH) return;
  double A[3][3];
  for (int r = 0; r < 3; ++r)
    for (int c = 0; c < 3; ++c) A[r][c] = (double)Hm[b * 9 + r * 3 + c];
  double S[3][3];
  for (int i = 0; i < 3; ++i)
    for (int j = 0; j < 3; ++j) {
      double acc = 0.0;
      for (int k = 0; k < 3; ++k) acc += A[k][i] * A[k][j];
      S[i][j] = acc;
    }
  double V[3][3] = {{1, 0, 0}, {0, 1, 0}, {0, 0, 1}};
  const int PP[3] = {0, 0, 1}, QQ[3] = {1, 2, 2};
  for (int sweep = 0; sweep < 40; ++sweep) {
    for (int pi = 0; pi < 3; ++pi) {
      int p = PP[pi], q = QQ[pi];
      double apq = S[p][q];
      if (fabs(apq) < 1e-300) continue;
      double tau = (S[q][q] - S[p][p]) / (2.0 * apq);
      double tt = (tau >= 0.0) ? 1.0 / (tau + sqrt(1.0 + tau * tau))
                               : 1.0 / (tau - sqrt(1.0 + tau * tau));
      double c = 1.0 / sqrt(1.0 + tt * tt), s = tt * c;
      for (int k = 0; k < 3; ++k) {
        double skp = S[k][p], skq = S[k][q];
        S[k][p] = c * skp - s * skq;
        S[k][q] = s * skp + c * skq;
      }
      for (int k = 0; k < 3; ++k) {
        double spk = S[p][k], sqk = S[q][k];
        S[p][k] = c * spk - s * sqk;
        S[q][k] = s * spk + c * sqk;
      }
      for (int k = 0; k < 3; ++k) {
        double vkp = V[k][p], vkq = V[k][q];
        V[k][p] = c * vkp - s * vkq;
        V[k][q] = s * vkp + c * vkq;
      }
    }
  }
  double ev[3] = {S[0][0], S[1][1], S[2][2]};
  int ord[3] = {0, 1, 2};
  for (int i = 0; i < 2; ++i)
    for (int j = i + 1; j < 3; ++j)
      if (ev[ord[j]] > ev[ord[i]]) { int tmp = ord[i]; ord[i] = ord[j]; ord[j] = tmp; }
  double Vv[3][3], Us[3][3];
  for (int i = 0; i < 3; ++i)
    for (int r = 0; r < 3; ++r) Vv[r][i] = V[r][ord[i]];
  for (int i = 0; i < 3; ++i) {
    double v0 = Vv[0][i], v1 = Vv[1][i], v2 = Vv[2][i];
    double u0 = A[0][0] * v0 + A[0][1] * v1 + A[0][2] * v2;
    double u1 = A[1][0] * v0 + A[1][1] * v1 + A[1][2] * v2;
    double u2 = A[2][0] * v0 + A[2][1] * v1 + A[2][2] * v2;
    double nrm = sqrt(u0 * u0 + u1 * u1 + u2 * u2);
    if (nrm > 1e-30) { u0 /= nrm; u1 /= nrm; u2 /= nrm; }
    else if (i == 2) {
      u0 = Us[1][0] * Us[2][1] - Us[2][0] * Us[1][1];
      u1 = Us[2][0] * Us[0][1] - Us[0][0] * Us[2][1];
      u2 = Us[0][0] * Us[1][1] - Us[1][0] * Us[0][1];
      double nn = sqrt(u0 * u0 + u1 * u1 + u2 * u2);
      if (nn > 1e-30) { u0 /= nn; u1 /= nn; u2 /= nn; }
    }
    Us[0][i] = u0; Us[1][i] = u1; Us[2][i] = u2;
  }
  double d = det3d(Vv) * det3d(Us);
  double R[3][3];
  for (int i = 0; i < 3; ++i)
    for (int j = 0; j < 3; ++j)
      R[i][j] = Vv[i][0] * Us[j][0] + Vv[i][1] * Us[j][1] + d * Vv[i][2] * Us[j][2];
  double sc[3] = {(double)cent[b * 6 + 0], (double)cent[b * 6 + 1], (double)cent[b * 6 + 2]};
  double tc[3] = {(double)cent[b * 6 + 3], (double)cent[b * 6 + 4], (double)cent[b * 6 + 5]};
  for (int r = 0; r < 3; ++r)
    for (int c = 0; c < 3; ++c) out[b * 9 + r * 3 + c] = (float)R[r][c];
  for (int i = 0; i < 3; ++i) {
    double tv = tc[i] - (R[i][0] * sc[0] + R[i][1] * sc[1] + R[i][2] * sc[2]);
    out[36 + b * 3 + i] = (float)tv;
  }
}

// ---------------------------------------------------------------- launch
extern "C" void kernel_launch(void* const* d_in, const int* in_sizes, int n_in,
                              void* d_out, int out_size, void* d_ws, size_t ws_size,
                              hipStream_t stream) {
  const float* src  = (const float*)d_in[0];
  const float* tgt  = (const float*)d_in[1];
  const float* g_w1 = (const float*)d_in[2];
  const float* g_s1 = (const float*)d_in[3];
  const float* g_b1 = (const float*)d_in[4];
  const float* g_w2 = (const float*)d_in[5];
  const float* g_s2 = (const float*)d_in[6];
  const float* g_b2 = (const float*)d_in[7];
  const float* g_wo = (const float*)d_in[8];
  const float* g_so = (const float*)d_in[9];
  const float* g_bo = (const float*)d_in[10];
  const float* q_w  = (const float*)d_in[11];
  const float* q_b  = (const float*)d_in[12];
  const float* k_w  = (const float*)d_in[13];
  const float* k_b  = (const float*)d_in[14];
  const float* v_w  = (const float*)d_in[15];
  const float* v_b  = (const float*)d_in[16];
  const float* m_w  = (const float*)d_in[17];
  const float* m_b  = (const float*)d_in[18];
  const float* mlp_w = (const float*)d_in[19];
  float* out = (float*)d_out;
  float* ws = (float*)d_ws;

  const size_t SLOT = 4194304;  // 16 MB slots
  float* d0   = ws + 0 * SLOT;
  float* d1   = ws + 1 * SLOT;
  float* Q0   = ws + 2 * SLOT;
  unsigned short* K0 = (unsigned short*)(ws + 3 * SLOT);
  unsigned short* V0 = (unsigned short*)(ws + 4 * SLOT);
  float* Q1   = ws + 5 * SLOT;
  unsigned short* K1 = (unsigned short*)(ws + 6 * SLOT);
  unsigned short* V1 = (unsigned short*)(ws + 7 * SLOT);
  float* att0 = ws + 8 * SLOT;
  float* att1 = ws + 9 * SLOT;
  float* mp0 = Q0;   // Q0 dead after attention
  float* mp1 = Q1;   // Q1 dead after attention
  float* d0n = att0; // att0 dead after m-proj
  float* d1n = att1;
  float* Sb = ws;    // sinkhorn buffer overlaps d0..V0 (dead by dists time)
  int*   idx0 = (int*)(ws + 6 * SLOT);        // K1 slot reused pre-attention? No:
  // careful: idx0/idx1 and smalls must not clash with live K1/V1. Put them in slot 5's tail
  // region? Q1 slot is live pre-attention. Use the out-of-band tail: slots 0-9 end at 160MB.
  idx0 = (int*)(ws + 10 * SLOT);
  int*   idx1 = idx0 + BATCH * NP * KNNK;
  float* colM = ws + 10 * SLOT + 327680;
  float* colS = colM + BATCH * NP * 8;
  float* colL = colS + BATCH * NP * 8;
  float* weights = colL + BATCH * NP;
  float* wsum = weights + BATCH * NP;
  float* wtg  = wsum + BATCH;
  float* cent = wtg + BATCH * 3 * NP;
  float* Hmb  = cent + BATCH * 6;

  // 1. kNN
  knn_kernel<<<BATCH * NP, 256, 0, stream>>>(src, idx0);
  knn_kernel<<<BATCH * NP, 256, 0, stream>>>(tgt, idx1);
  // 2. GAC
  gac_kernel<<<BATCH * NP, 256, 0, stream>>>(src, idx0, g_w1, g_s1, g_b1, g_w2, g_s2, g_b2,
                                             g_wo, g_so, g_bo, d0);
  gac_kernel<<<BATCH * NP, 256, 0, stream>>>(tgt, idx1, g_w1, g_s1, g_b1, g_w2, g_s2, g_b2,
                                             g_wo, g_so, g_bo, d1);
  // 3. Q/K/V projections (head-split layouts; K bf16, V bf16-transposed)
  dim3 gp(NP / 64, DEMB / 64, BATCH);
  gemm_bias_kernel<1><<<gp, 256, 0, stream>>>(q_w, q_b, d0, Q0, DEMB);
  gemm_bias_kernel<2><<<gp, 256, 0, stream>>>(k_w, k_b, d0, K0, DEMB);
  gemm_bias_kernel<3><<<gp, 256, 0, stream>>>(v_w, v_b, d0, V0, DEMB);
  gemm_bias_kernel<1><<<gp, 256, 0, stream>>>(q_w, q_b, d1, Q1, DEMB);
  gemm_bias_kernel<2><<<gp, 256, 0, stream>>>(k_w, k_b, d1, K1, DEMB);
  gemm_bias_kernel<3><<<gp, 256, 0, stream>>>(v_w, v_b, d1, V1, DEMB);
  // 4. cross attention (MFMA)
  attn_mfma_kernel<<<16 * 32, 256, 0, stream>>>(Q0, K1, V1, att0);
  attn_mfma_kernel<<<16 * 32, 256, 0, stream>>>(Q1, K0, V0, att1);
  // 5. message projection
  gemm_bias_kernel<0><<<gp, 256, 0, stream>>>(m_w, m_b, att0, mp0, DEMB);
  gemm_bias_kernel<0><<<gp, 256, 0, stream>>>(m_w, m_b, att1, mp1, DEMB);
  // 6. MLP + residual
  gemm_mlp_kernel<<<gp, 256, 0, stream>>>(mlp_w, d0, mp0, d0, d0n);
  gemm_mlp_kernel<<<gp, 256, 0, stream>>>(mlp_w, d1, mp1, d1, d1n);
  // 7. dists into padded sinkhorn buffer
  dim3 gd(NP / 64, NP / 64, BATCH);
  dists_kernel<<<gd, 256, 0, stream>>>(d0n, d1n, Sb);
  sink_pad_kernel<<<(BATCH * NP1 + 255) / 256, 256, 0, stream>>>(Sb);
  // 8. sinkhorn, 5 iterations
  for (int it = 0; it < 5; ++it) {
    sink_row_kernel<<<BATCH * NP, 256, 0, stream>>>(Sb);
    sink_col1_kernel<<<dim3(NP / 64, 8, BATCH), 256, 0, stream>>>(Sb, colM, colS);
    sink_col2_kernel<<<(BATCH * NP + 255) / 256, 256, 0, stream>>>(colM, colS, colL);
    sink_col3_kernel<<<BATCH * NP1, 256, 0, stream>>>(Sb, colL);
  }
  // 9. perm_norm (to out) + weights + weighted_tgt
  perm_kernel<<<BATCH * NP, 256, 0, stream>>>(Sb, tgt, out + 48, weights, wtg);
  // 10. Kabsch
  wsum_kernel<<<BATCH, 256, 0, stream>>>(weights, wsum);
  cent_hm_kernel<<<BATCH, 256, 0, stream>>>(src, wtg, weights, wsum, cent, Hmb);
  solve_kernel<<<1, 64, 0, stream>>>(Hmb, cent, out);
}